// Round 10
// baseline (11973.402 us; speedup 1.0000x reference)
//
#include <hip/hip_runtime.h>
#include <math.h>

#define DZ 128
#define DX 64
#define KMIX 16
#define JITTER_C 1e-4f
#define MS (DZ*DZ)            // 16384
#define ESZ (4*MS + 2*DZ)     // element: A, At, C, J, b, eta
#define NCH 256               // chunks
#define NT 1024               // threads per block (16 waves, 4/SIMD)
#define SCN (3*MS + 256)      // per-chunk scratch floats (passA:3, scan:1)

typedef unsigned short ushortT;
typedef unsigned int uintT;

// =====================================================================
// mm_: out[MxN] = op( sum_k At[k*M+i] * B[k*N+j] )  i.e. out = (At)^T*B
// MODE 0: store; 1: out += acc; 2: out = aux - acc; 3: out = aux + acc
// MODE 4: out = acc + e1*aux + I   (aux may alias out; per-thread tiles)
// DUAL: additionally store transposed result to outT (N x M).
// Wave-skewed K loop.
// =====================================================================
template<int M, int N, int K, int MODE, bool DUAL>
__device__ void mm_(const float* __restrict__ At, const float* __restrict__ B,
                    float* __restrict__ out, const float* __restrict__ aux,
                    float* __restrict__ outT, float e1 = 0.f)
{
    __syncthreads();
    const int tid = threadIdx.x;
    constexpr int TM = M/32, TN = N/32;
    const int tx = tid & 31, ty = tid >> 5;
    const int i0 = ty*TM, j0 = tx*TN;
    float acc[TM*TN];
#pragma unroll
    for (int e = 0; e < TM*TN; ++e) acc[e] = 0.f;
    auto body = [&](int k) {
        const float* ar = At + k*M + i0;
        const float* br = B + k*N + j0;
        float av[TM], bv[TN];
        if constexpr (TM == 2) {
            float2 t = *reinterpret_cast<const float2*>(ar);
            av[0]=t.x; av[1]=t.y;
        } else {
#pragma unroll
            for (int a = 0; a < TM; a += 4) {
                float4 t = *reinterpret_cast<const float4*>(ar + a);
                av[a]=t.x; av[a+1]=t.y; av[a+2]=t.z; av[a+3]=t.w;
            }
        }
        if constexpr (TN == 2) {
            float2 t = *reinterpret_cast<const float2*>(br);
            bv[0]=t.x; bv[1]=t.y;
        } else {
#pragma unroll
            for (int b = 0; b < TN; b += 4) {
                float4 t = *reinterpret_cast<const float4*>(br + b);
                bv[b]=t.x; bv[b+1]=t.y; bv[b+2]=t.z; bv[b+3]=t.w;
            }
        }
#pragma unroll
        for (int a = 0; a < TM; ++a)
#pragma unroll
            for (int b = 0; b < TN; ++b)
                acc[a*TN+b] = fmaf(av[a], bv[b], acc[a*TN+b]);
    };
    const int off = (tid >> 6) * (K >> 4);
#pragma unroll 8
    for (int k = off; k < K; ++k) body(k);
#pragma unroll 8
    for (int k = 0; k < off; ++k) body(k);
#pragma unroll
    for (int a = 0; a < TM; ++a) {
#pragma unroll
        for (int b = 0; b < TN; ++b) {
            const int row = i0+a, col = j0+b;
            const int idx = row*N + col;
            float v = acc[a*TN+b];
            if constexpr (MODE == 1) v += out[idx];
            else if constexpr (MODE == 2) v = aux[idx] - v;
            else if constexpr (MODE == 3) v += aux[idx];
            else if constexpr (MODE == 4) { v += e1*aux[idx]; if (row==col) v += 1.f; }
            out[idx] = v;
            acc[a*TN+b] = v;
        }
    }
    if constexpr (DUAL) {
#pragma unroll
        for (int b = 0; b < TN; ++b) {
#pragma unroll
            for (int a = 0; a < TM; a += 4) {
                float4 v = make_float4(acc[(a)*TN+b], acc[(a+1)*TN+b], acc[(a+2)*TN+b], acc[(a+3)*TN+b]);
                *reinterpret_cast<float4*>(outT + (j0+b)*M + i0 + a) = v;
            }
        }
    }
    __syncthreads();
}

// =====================================================================
// mv_: out[i] = op(aux[i], sum_k At[k*M+i]*v[k]) — NT/M threads per row.
// MODE 0: sum; 1: aux + sum; 2: aux - sum
// =====================================================================
template<int M, int K, int MODE>
__device__ void mv_(const float* __restrict__ At, const float* __restrict__ v,
                    float* __restrict__ out, const float* __restrict__ aux)
{
    __syncthreads();
    const int tid = threadIdx.x;
    constexpr int TPR = NT / M;
    constexpr int CH  = K / TPR;
    const int r  = tid / TPR;
    const int sg = tid % TPR;
    const int k0 = sg * CH;
    float s = 0.f;
#pragma unroll
    for (int k = 0; k < CH; ++k)
        s = fmaf(At[(k0 + k)*M + r], v[k0 + k], s);
#pragma unroll
    for (int o = 1; o < TPR; o <<= 1) s += __shfl_xor(s, o);
    if (sg == 0) {
        float rr;
        if constexpr (MODE == 0) rr = s;
        else if constexpr (MODE == 1) rr = aux[r] + s;
        else rr = aux[r] - s;
        out[r] = rr;
    }
    __syncthreads();
}

// dst[NxM] = src[MxN]^T via XOR-swizzled LDS bounce (128x128 only).
__device__ void trans_g(const float* __restrict__ src, float* __restrict__ dst,
                        float* __restrict__ Lb)
{
    __syncthreads();
    for (int e = threadIdx.x; e < MS; e += NT) {
        int i = e >> 7, j = e & 127;
        Lb[(i << 7) + (j ^ (i & 31))] = src[e];
    }
    __syncthreads();
    for (int e = threadIdx.x; e < MS; e += NT) {
        int a = e >> 7, b = e & 127;
        dst[e] = Lb[(b << 7) + (a ^ (b & 31))];
    }
    __syncthreads();
}

// =====================================================================
// gj64_spd: rank-4 block Gauss-Jordan inverse of SPD 64x64 in LDS.
// =====================================================================
__device__ void gj64_spd(float* __restrict__ A, float* __restrict__ st)
{
    const int tid = threadIdx.x;
    for (int p = 0; p < DX; p += 4) {
        __syncthreads();
        if (tid < 64) {
#pragma unroll
            for (int b = 0; b < 4; ++b) st[tid*4+b] = A[tid*DX + p + b];
        } else if (tid < 128) {
            int j = tid - 64;
#pragma unroll
            for (int b = 0; b < 4; ++b) st[256 + b*64 + j] = A[(p+b)*DX + j];
        }
        __syncthreads();
        float Dm[16], Di[16];
#pragma unroll
        for (int a = 0; a < 4; ++a)
#pragma unroll
            for (int b = 0; b < 4; ++b) {
                Dm[a*4+b] = st[(p+a)*4 + b];
                Di[a*4+b] = (a==b) ? 1.f : 0.f;
            }
#pragma unroll
        for (int q = 0; q < 4; ++q) {
            float rp = 1.f / Dm[q*4+q];
#pragma unroll
            for (int j = 0; j < 4; ++j) { Dm[q*4+j] *= rp; Di[q*4+j] *= rp; }
#pragma unroll
            for (int i = 0; i < 4; ++i) {
                if (i == q) continue;
                float f = Dm[i*4+q];
#pragma unroll
                for (int j = 0; j < 4; ++j) { Dm[i*4+j] = fmaf(-f, Dm[q*4+j], Dm[i*4+j]); Di[i*4+j] = fmaf(-f, Di[q*4+j], Di[i*4+j]); }
            }
        }
        for (int e = tid; e < DX*DX; e += NT) {
            const int i = e >> 6, j = e & 63;
            const bool iP = (i >= p) && (i < p+4);
            const bool jP = (j >= p) && (j < p+4);
            float o;
            if (iP && jP) {
                o = Di[(i-p)*4 + (j-p)];
            } else if (iP) {
                const int a = i - p;
                o = Di[a*4+0]*st[256+0*64+j] + Di[a*4+1]*st[256+1*64+j]
                  + Di[a*4+2]*st[256+2*64+j] + Di[a*4+3]*st[256+3*64+j];
            } else {
                float Ei[4];
#pragma unroll
                for (int b = 0; b < 4; ++b)
                    Ei[b] = st[i*4+0]*Di[0*4+b] + st[i*4+1]*Di[1*4+b]
                          + st[i*4+2]*Di[2*4+b] + st[i*4+3]*Di[3*4+b];
                if (jP) o = -Ei[j-p];
                else    o = A[e] - (Ei[0]*st[256+0*64+j] + Ei[1]*st[256+1*64+j]
                                  + Ei[2]*st[256+2*64+j] + Ei[3]*st[256+3*64+j]);
            }
            A[e] = o;
        }
    }
    __syncthreads();
}

// =====================================================================
// gj128_piv: partial-pivoted GJ of 128x128 in LDS; wave-0 shfl argmax.
// =====================================================================
__device__ void gj128_piv(float* __restrict__ A, float* __restrict__ pc, float* __restrict__ pr,
                          int* __restrict__ rec, int* __restrict__ ipv1)
{
    __syncthreads();
    const int tid = threadIdx.x;
    for (int p = 0; p < DZ; ++p) {
        if (tid < 64) {
            float best = -1.f; int bi = p;
            for (int i = tid; i < DZ; i += 64) {
                float v = (i >= p) ? fabsf(A[i*DZ + p]) : -2.f;
                if (v > best) { best = v; bi = i; }
            }
            for (int off = 32; off > 0; off >>= 1) {
                float ob = __shfl_xor(best, off);
                int obi = __shfl_xor(bi, off);
                if (ob > best) { best = ob; bi = obi; }
            }
            if (tid == 0) { rec[p] = bi; ipv1[0] = bi; }
        }
        __syncthreads();
        const int r = ipv1[0];
        if (r != p) {
            for (int j = tid; j < DZ; j += NT) { float t = A[p*DZ+j]; A[p*DZ+j] = A[r*DZ+j]; A[r*DZ+j] = t; }
            __syncthreads();
        }
        if (tid < DZ) { pc[tid] = A[tid*DZ + p]; pr[tid] = A[p*DZ + tid]; }
        __syncthreads();
        const float rp = 1.f / pr[p];
        for (int e = tid; e < MS; e += NT) {
            const int i = e >> 7, j = e & 127;
            const float pv = pr[j] * rp;
            float o;
            if (i == p) o = (j == p) ? rp : pv;
            else { const float fc = pc[i]; o = (j == p) ? (-fc*rp) : (A[e] - fc*pv); }
            A[e] = o;
        }
        __syncthreads();
    }
    for (int p = DZ - 1; p >= 0; --p) {
        const int r = rec[p];
        if (r != p) {
            for (int i = tid; i < DZ; i += NT) { float t = A[i*DZ+p]; A[i*DZ+p] = A[i*DZ+r]; A[i*DZ+r] = t; }
            __syncthreads();
        }
    }
    __syncthreads();
}

// =====================================================================
// phase1_dev: slim step map, X sourced from PRECOMPUTED bf16 Xb:
//   F = I + g1 X + (g2 I + g3 X) X^2      -> Ft in L0 (LDS)
//   Q = h (g1 D + W1 D + D W1^T)          -> s3
//   c = h (g1 + g2 X + g3 X^2 + g4 X^3) eb -> cvec
// =====================================================================
__device__ void phase1_dev(int k,
    const ushortT* __restrict__ Xb, const float* __restrict__ hbuf,
    const float* __restrict__ wn,
    const float* __restrict__ b_s, const float* __restrict__ Qch,
    float* s1, float* s2, float* s3,
    float* L0, float* L1,
    float* W16, float* ebv, float* eqv, float* vvv, float* cvec,
    float g1, float g2, float g3, float g4)
{
    const int tid = threadIdx.x;
    const float h = hbuf[k];
    if (h <= 0.f) {
        __syncthreads();
        for (int e = tid; e < MS; e += NT) {
            int i = e >> 7, j = e & 127;
            L0[e] = (i==j) ? 1.f : 0.f;
            s3[e] = 0.f;
        }
        if (tid < DZ) cvec[tid] = 0.f;
        __syncthreads();
        return;
    }
    __syncthreads();
    if (tid < KMIX) W16[tid] = wn[(size_t)k*KMIX + tid];
    __syncthreads();
    if (tid < DZ) {
        float eb = 0.f, eq = 0.f;
        for (int m = 0; m < KMIX; ++m) {
            float wm = W16[m];
            eb = fmaf(wm, b_s[m*DZ+tid], eb);
            float qc = Qch[m*DZ+tid];
            eq = fmaf(wm, qc*qc, eq);
        }
        ebv[tid] = eb; eqv[tid] = eq;
    }
    // load X (bf16) -> L1 (X) and L0 (Xt)
    {
        const uint4* xr = reinterpret_cast<const uint4*>(Xb + (size_t)k*MS);
        for (int e8 = tid; e8 < MS/8; e8 += NT) {
            uint4 pk = xr[e8];
            int base = e8*8; int i = base >> 7; int j = base & 127;
            uintT uu[4] = {pk.x, pk.y, pk.z, pk.w};
#pragma unroll
            for (int t = 0; t < 4; ++t) {
                float lo = __uint_as_float(uu[t] << 16);
                float hi = __uint_as_float(uu[t] & 0xFFFF0000u);
                L1[base + 2*t]     = lo;
                L1[base + 2*t + 1] = hi;
                L0[(j + 2*t)*DZ + i]     = lo;
                L0[(j + 2*t + 1)*DZ + i] = hi;
            }
        }
    }
    __syncthreads();
    // cvec: 3 power iterations
    {
        float gg[5]; gg[1]=g1; gg[2]=g2; gg[3]=g3; gg[4]=g4;
        if (tid < DZ) vvv[tid] = ebv[tid];
        float creg = (tid < DZ) ? g1 * ebv[tid] : 0.f;
        __syncthreads();
        for (int m = 1; m <= 3; ++m) {
            float vn = 0.f;
            if (tid < DZ)
                for (int kk = 0; kk < DZ; ++kk)
                    vn = fmaf(L0[kk*DZ + tid], vvv[kk], vn);
            __syncthreads();
            if (tid < DZ) vvv[tid] = vn;
            creg = fmaf(gg[m+1], vn, creg);
            __syncthreads();
        }
        if (tid < DZ) cvec[tid] = h * creg;
    }
    // X2 (dual)
    mm_<128,128,128,0,true>(L0, L1, s1, nullptr, s2);
    // Q -> s3 ; Mt -> L1 (X dead per-element)
    for (int e = tid; e < MS; e += NT) {
        int j = e >> 7, i = e & 127;
        float xe = L1[e];
        float xt = L0[e];
        float w1  = g2*xe + g3*s1[e];
        float w1t = g2*xt + g3*s2[e];
        float vq = w1*eqv[i] + eqv[j]*w1t;
        if (i == j) vq += g1*eqv[j];
        s3[e] = h * vq;
        L1[e] = g3*xt + ((i==j) ? g2 : 0.f);
    }
    __syncthreads();
    // Ft = X2^T Mt + g1 Xt + I -> L0
    mm_<128,128,128,4,false>(s1, L1, L0, L0, nullptr, g1);
}

#define SHARED_DECLS \
    __shared__ __align__(16) float L0[MS]; \
    __shared__ __align__(16) float L1[MS]; \
    __shared__ __align__(16) float SL[DX*DX]; \
    __shared__ __align__(16) float GJB[520]; \
    __shared__ float V0[DZ],V1[DZ],V2[DZ],V3[DZ],V4[DZ],V5[DZ]; \
    __shared__ float r64s[DX], u64s[DX]; \
    __shared__ float W16[KMIX], ebv[DZ], eqv[DZ], vvv[DZ], cvec[DZ]; \
    __shared__ float GJc[DZ], GJr[DZ]; \
    __shared__ int REC[DZ]; __shared__ int IPV1[1];

// =====================================================================
// wprep: normalized weights + step sizes
// =====================================================================
__global__ __launch_bounds__(256) void kf_wprep(
    const float* __restrict__ es, const float* __restrict__ ts,
    float* __restrict__ wn, float* __restrict__ hbuf, int T)
{
    int k = blockIdx.x*256 + threadIdx.x;
    if (k >= T) return;
    float w[KMIX]; float s = 0.f;
    for (int m = 0; m < KMIX; ++m) { w[m] = es[(size_t)k*KMIX+m]; s += w[m]; }
    float inv = 1.f/s;
    for (int m = 0; m < KMIX; ++m) wn[(size_t)k*KMIX+m] = w[m]*inv;
    hbuf[k] = (k >= 1) ? (ts[k]-ts[k-1]) : 0.f;
}

// =====================================================================
// xprep: X_k = h_k * sum_m w_m A_m stored bf16. A_s row-tile in LDS.
// grid: 16 rtiles x 16 step-groups = 256 blocks.
// =====================================================================
__global__ __launch_bounds__(NT) void kf_xprep(
    const float* __restrict__ A_s, const float* __restrict__ wn,
    const float* __restrict__ hbuf, ushortT* __restrict__ Xb, int T)
{
    __shared__ float Al[16*8*128];
    __shared__ float wloc[KMIX];
    const int tid = threadIdx.x;
    const int rt = blockIdx.x & 15, sg = blockIdx.x >> 4;
    const int r0 = rt*8;
    for (int i4 = tid; i4 < 4096; i4 += NT) {
        int m = i4 >> 8, rem = i4 & 255;
        int r = rem >> 5, c4 = rem & 31;
        float4 v = *reinterpret_cast<const float4*>(A_s + (size_t)m*MS + (size_t)(r0+r)*DZ + c4*4);
        *reinterpret_cast<float4*>(&Al[m*1024 + r*128 + c4*4]) = v;
    }
    __syncthreads();
    const int spg = (T + 15) >> 4;
    int k0 = sg*spg; int k1 = k0 + spg; if (k1 > T) k1 = T;
    if (k0 < 1) k0 = 1;
    const int rr = tid >> 7, col = tid & 127;
    for (int k = k0; k < k1; ++k) {
        if (tid < KMIX) wloc[tid] = wn[(size_t)k*KMIX + tid];
        __syncthreads();
        float hk = hbuf[k];
        float s = 0.f;
#pragma unroll
        for (int m = 0; m < KMIX; ++m)
            s = fmaf(wloc[m], Al[m*1024 + rr*128 + col], s);
        float v = hk * s;
        uintT u = __float_as_uint(v);
        u += 0x7FFFu + ((u >> 16) & 1u);
        Xb[(size_t)k*MS + (size_t)(r0+rr)*DZ + col] = (ushortT)(u >> 16);
        __syncthreads();
    }
}

// =====================================================================
// prep: Ct, Rj, Rji, initial updated state (mu0u, p0u)
// =====================================================================
__global__ __launch_bounds__(NT) void kf_prep(
    const float* __restrict__ Cm, const float* __restrict__ Rm,
    const float* __restrict__ mu0, const float* __restrict__ P0,
    const float* __restrict__ xs,
    float* Ct, float* Rj, float* Rji, float* mu0u, float* p0u, float* scr)
{
    SHARED_DECLS
    const int tid = threadIdx.x;
    for (int i = tid; i < DZ*DX; i += NT) { int z = i>>6, m = i&63; Ct[i] = Cm[m*DZ + z]; }
    for (int i = tid; i < DX*DX; i += NT) {
        int a = i>>6, b = i&63;
        float v = Rm[i] + ((a==b) ? JITTER_C : 0.f);
        Rj[i] = v; SL[i] = v;
    }
    gj64_spd(SL, GJB);
    for (int i = tid; i < DX*DX; i += NT) Rji[i] = SL[i];
    float* z  = scr;
    float* cp = scr + DZ*DX;
    float* kt = scr + MS;
    mm_<128,64,128,0,true>(P0, Ct, z, nullptr, cp);     // z = P0 C^T, cp = C P0
    mm_<64,64,128,3,false>(Ct, z, SL, Rj, nullptr);     // S0
    gj64_spd(SL, GJB);
    mm_<64,128,64,0,false>(SL, cp, kt, nullptr, nullptr); // K0^T
    mv_<64,128,2>(Ct, mu0, r64s, xs);                   // r = x0 - C mu0
    mv_<128,64,1>(kt, r64s, mu0u, mu0);                 // mu0u = mu0 + K0 r
    mm_<128,128,64,2,false>(kt, cp, p0u, P0, nullptr);  // P0u = P0 - K0 C P0
    __syncthreads();
    for (int e = tid; e < MS; e += NT) L0[e] = p0u[e];
    __syncthreads();
    for (int e = tid; e < MS; e += NT) {
        int i = e>>7, j = e&127;
        p0u[e] = 0.5f * (L0[e] + L0[j*DZ + i]);
    }
}

// =====================================================================
// pass A: per chunk, element recursion (predict + Woodbury update)
// =====================================================================
__global__ __launch_bounds__(NT) void kf_passA(
    const float* __restrict__ xs,
    const float* __restrict__ Ct, const float* __restrict__ Rj,
    const float* __restrict__ Rji,
    const float* __restrict__ mu0u, const float* __restrict__ p0u,
    const float* __restrict__ b_s, const float* __restrict__ Qch,
    const float* __restrict__ wn, const float* __restrict__ hbuf,
    const ushortT* __restrict__ Xb,
    float* elems, float* scr, int T, int LCH,
    float g1, float g2, float g3, float g4)
{
    SHARED_DECLS
    const int c = blockIdx.x, tid = threadIdx.x;
    float* sc = scr + (size_t)c * SCN;
    float* R = elems + (size_t)c * ESZ;
    float* RAs = R; float* RAts = R+MS; float* RCs = R+2*MS; float* RJs = R+3*MS;
    float* Rbs = R+4*MS; float* Rhs = R+4*MS+DZ;
    int eBeg = c*LCH, eEnd = (c*LCH + LCH < T) ? (c*LCH + LCH) : T;
    if (eBeg >= eEnd && c != 0) {
        for (int e = tid; e < MS; e += NT) {
            int i = e>>7, j = e&127; float id = (i==j)?1.f:0.f;
            RAs[e]=id; RAts[e]=id; RCs[e]=0.f; RJs[e]=0.f;
        }
        if (tid < DZ) { Rbs[tid]=0.f; Rhs[tid]=0.f; }
        return;
    }
    if (c == 0) {
        for (int e = tid; e < MS; e += NT) { RAs[e]=0.f; RCs[e]=p0u[e]; RJs[e]=0.f; }
        if (tid < DZ) { V0[tid]=mu0u[tid]; V5[tid]=0.f; }
        eBeg = 1;
    } else {
        for (int e = tid; e < MS; e += NT) {
            int i = e>>7, j = e&127;
            RAs[e] = (i==j)?1.f:0.f; RCs[e]=0.f; RJs[e]=0.f;
        }
        if (tid < DZ) { V0[tid]=0.f; V5[tid]=0.f; }
    }
    __syncthreads();
    float* s1 = sc; float* s2 = sc + MS; float* s3 = sc + 2*MS;
    float* z  = L0;    float* zt = L0 + 8192;
    for (int e = eBeg; e < eEnd; ++e) {
        phase1_dev(e, Xb, hbuf, wn, b_s, Qch, s1, s2, s3, L0, L1,
                   W16, ebv, eqv, vvv, cvec, g1, g2, g3, g4);
        // ---- predict-compose (EJ=0); Ft in L0, Q in s3 ----
        mm_<128,128,128,0,false>(L0, RAs, s2, nullptr, nullptr);   // tA -> s2 (X2T dead)
        mv_<128,128,1>(L0, V0, V1, cvec);                          // Rb' = F Rb + c
        mm_<128,128,128,0,false>(RCs, L0, s1, nullptr, nullptr);   // tU -> s1 (X2 dead)
        mm_<128,128,128,3,false>(L0, s1, L1, s3, nullptr);         // RC' = F tU + Q -> L1
        // ---- update-compose (Woodbury); Z/Zt in LDS ----
        mm_<128,64,128,0,true>(L1, Ct, z, nullptr, zt);            // Z = RC' C^T (dual)
        mm_<64,64,128,3,false>(Ct, z, SL, Rj, nullptr);            // S~ = R~ + C Z
        gj64_spd(SL, GJB);                                         // SL = S~^-1
        mm_<64,128,128,0,false>(Ct, s2, s3, nullptr, nullptr);     // y = C tA -> s3
        mm_<64,128,64,0,false>(SL, s3, s3 + 8192, nullptr, nullptr); // hh = Si y
        mm_<128,128,64,2,false>(zt, s3 + 8192, RAs, s2, nullptr);  // RA'' = tA - Z hh
        mm_<128,128,64,1,false>(s3, s3 + 8192, RJs, nullptr, nullptr); // RJ += y^T hh
        mm_<64,128,64,0,false>(SL, zt, s2, nullptr, nullptr);      // h2 = Si Z^T (tA dead)
        mm_<128,128,64,2,false>(zt, s2, RCs, L1, nullptr);         // RC'' = RC' - Z h2
        // vectors
        mv_<64,128,2>(Ct, V1, r64s, xs + (size_t)e*DX);            // r = x - C Rb'
        mv_<64,64,0>(Rji, xs + (size_t)e*DX, u64s, nullptr);       // u = R~i x
        mv_<128,64,1>(zt, u64s, V2, V1);                           // v1 = Rb' + Z u
        mv_<64,128,0>(Ct, V2, GJc, nullptr);                       // w = C v1
        mv_<64,64,0>(SL, GJc, GJr, nullptr);                       // w2 = Si w
        mv_<128,64,2>(zt, GJr, V0, V2);                            // Rb'' = v1 - Z w2
        mv_<64,64,0>(SL, r64s, u64s, nullptr);                     // s = Si r
        mv_<128,64,1>(s3, u64s, V5, V5);                           // Reta += y^T s
    }
    __syncthreads();
    if (tid < DZ) { Rbs[tid] = V0[tid]; Rhs[tid] = V5[tid]; }
    trans_g(RAs, RAts, L0);
}

// =====================================================================
// combine: D <- Rsrc (earlier) (x) E (later). No pre-copy of Rsrc needed.
// t1/t3 live in L1 (LDS); one global slot sa.
// =====================================================================
__device__ void combine(float* D, const float* Rsrc, const float* E,
    float* sa, float* L0, float* L1,
    float* V0, float* V1, float* V2, float* V3, float* V4, float* V5,
    float* GJc, float* GJr, int* REC, int* IPV1, int lastj)
{
    const float* RA_s = Rsrc;            const float* RC_s = Rsrc + 2*MS;
    const float* RJ_s = Rsrc + 3*MS;
    const float* Rb_s = Rsrc + 4*MS;     const float* Rh_s = Rsrc + 4*MS + DZ;
    const float* EAt  = E + MS;          const float* EC   = E + 2*MS;
    const float* EJ   = E + 3*MS;
    const float* Ebg  = E + 4*MS;        const float* Ehg  = E + 4*MS + DZ;
    float* D_RA = D; float* D_RAt = D+MS; float* D_RC = D+2*MS; float* D_RJ = D+3*MS;
    float* D_Rb = D+4*MS; float* D_Rh = D+4*MS+DZ;
    const int tid = threadIdx.x;
    __syncthreads();
    if (tid < DZ) { V0[tid]=Ebg[tid]; V1[tid]=Ehg[tid]; V2[tid]=Rb_s[tid]; }
    mm_<128,128,128,0,false>(EJ, RC_s, L0, nullptr, nullptr);  // L0 = EJ RC
    if (tid < DZ) L0[tid*DZ + tid] += 1.f;                     // M^T
    gj128_piv(L0, GJc, GJr, REC, IPV1);                        // L0 = M^-T
    if (!lastj) {
        mm_<128,128,128,0,false>(L0, RA_s, L1, nullptr, nullptr);  // t1 = Minv RA (LDS)
        mm_<128,128,128,0,false>(EJ, RA_s, sa, nullptr, nullptr);  // t2 = EJ RA
        mm_<128,128,128,3,false>(L1, sa, D_RJ, RJ_s, nullptr);     // D_RJ = t1^T t2 + RJ
        mv_<128,128,2>(EJ, V2, V4, V1);                            // w1 = Eh - EJ Rb
        mv_<128,128,1>(L1, V4, D_Rh, Rh_s);                        // D_Rh = Rh + t1^T w1
        mm_<128,128,128,0,false>(EAt, L1, D_RA, nullptr, nullptr); // D_RA = EA t1
        trans_g(D_RA, D_RAt, L1);                                  // t1 dead
    }
    mv_<128,128,1>(RC_s, V1, V3, V2);                          // v1 = Rb + RC Eh
    mv_<128,128,0>(L0, V3, V5, nullptr);                       // z1 = Minv v1
    mv_<128,128,1>(EAt, V5, D_Rb, V0);                         // D_Rb = Eb + EA z1
    mm_<128,128,128,0,false>(L0, RC_s, L1, nullptr, nullptr);  // t3 = Minv RC (LDS)
    mm_<128,128,128,0,false>(L1, EAt, sa, nullptr, nullptr);   // t2 = t3^T EA^T
    mm_<128,128,128,3,false>(EAt, sa, D_RC, EC, nullptr);      // D_RC = EA t2 + EC
}

// =====================================================================
// Kogge-Stone scan round (copy-eliminated for c >= r)
// =====================================================================
__global__ __launch_bounds__(NT) void kf_scan(
    const float* __restrict__ in, float* __restrict__ out, float* scr, int r, int lastj)
{
    SHARED_DECLS
    const int c = blockIdx.x;
    float* sc = scr + (size_t)c * SCN;
    float* dst = out + (size_t)c * ESZ;
    if (c >= r) {
        const float* Rsrc = in + (size_t)(c - r) * ESZ;
        const float* E = in + (size_t)c * ESZ;
        combine(dst, Rsrc, E, sc, L0, L1,
                V0,V1,V2,V3,V4,V5, GJc, GJr, REC, IPV1, lastj);
    } else {
        const float* src = in + (size_t)c * ESZ;
        if (lastj) {
            for (int e = threadIdx.x; e < MS; e += NT) dst[2*MS + e] = src[2*MS + e];
            for (int e = threadIdx.x; e < DZ; e += NT) dst[4*MS + e] = src[4*MS + e];
        } else {
            for (int e = threadIdx.x; e < ESZ; e += NT) dst[e] = src[e];
        }
    }
}

// =====================================================================
// pass C: plain filter from exact boundary state; scratch overlays elemsB.
// =====================================================================
__global__ __launch_bounds__(NT) void kf_passC(
    const float* __restrict__ xs,
    const float* __restrict__ Ct, const float* __restrict__ Rj,
    const float* __restrict__ mu0u, const float* __restrict__ p0u,
    const float* __restrict__ b_s, const float* __restrict__ Qch,
    const float* __restrict__ wn, const float* __restrict__ hbuf,
    const ushortT* __restrict__ Xb,
    const float* __restrict__ pfx,
    float* mu_out, float* P_out, float* scrC, int T, int LCH,
    float g1, float g2, float g3, float g4)
{
    SHARED_DECLS
    const int c = blockIdx.x, tid = threadIdx.x;
    float* sc = scrC + (size_t)c * ESZ;
    float* P = sc;
    float* s1 = sc + MS; float* s2 = sc + 2*MS; float* s3 = sc + 3*MS;
    int eBeg = c*LCH, eEnd = (c*LCH + LCH < T) ? (c*LCH + LCH) : T;
    if (eBeg >= eEnd && c != 0) return;
    if (c == 0) {
        for (int e = tid; e < MS; e += NT) { float v = p0u[e]; P[e] = v; P_out[e] = v; }
        if (tid < DZ) { V0[tid] = mu0u[tid]; mu_out[tid] = mu0u[tid]; }
        eBeg = 1;
    } else {
        const float* X = pfx + (size_t)(c-1) * ESZ;
        for (int e = tid; e < MS; e += NT) P[e] = X[2*MS + e];
        if (tid < DZ) V0[tid] = X[4*MS + tid];
    }
    __syncthreads();
    float* z  = L0;    float* zt = L0 + 8192;
    for (int e = eBeg; e < eEnd; ++e) {
        phase1_dev(e, Xb, hbuf, wn, b_s, Qch, s1, s2, s3, L0, L1,
                   W16, ebv, eqv, vvv, cvec, g1, g2, g3, g4);
        mm_<128,128,128,0,false>(P, L0, s2, nullptr, nullptr);     // U -> s2 (X2T dead)
        mm_<128,128,128,3,false>(L0, s2, L1, s3, nullptr);         // Ppr = F U + Q -> L1
        mv_<128,128,1>(L0, V0, V1, cvec);                          // mupr = F mu + c
        mm_<128,64,128,0,true>(L1, Ct, z, nullptr, zt);            // Z dual (LDS)
        mm_<64,64,128,3,false>(Ct, z, SL, Rj, nullptr);            // S
        gj64_spd(SL, GJB);
        mm_<64,128,64,0,false>(SL, zt, s2, nullptr, nullptr);      // kt = Si Z^T
        mv_<64,128,2>(Ct, V1, r64s, xs + (size_t)e*DX);            // y = x - C mupr
        mv_<128,64,1>(s2, r64s, V0, V1);                           // mu = mupr + K y
        if (tid < DZ) mu_out[(size_t)e*DZ + tid] = V0[tid];
        mm_<128,128,64,2,false>(zt, s2, L1, L1, nullptr);          // P_u = Ppr - Z kt
        for (int ee = tid; ee < MS; ee += NT) {
            int i = ee >> 7, j = ee & 127;
            L0[(i << 7) + (j ^ (i & 31))] = L1[ee];
        }
        __syncthreads();
        float* po = P_out + (size_t)e * MS;
        for (int ee = tid; ee < MS; ee += NT) {
            int i = ee >> 7, j = ee & 127;
            float v = 0.5f * (L1[ee] + L0[(j << 7) + (i ^ (j & 31))]);
            P[ee] = v;
            __builtin_nontemporal_store(v, &po[ee]);
        }
        __syncthreads();
    }
}

// =====================================================================
// host: RK stability polynomial coefficients
// =====================================================================
static void compute_gamma(double g[7])
{
    const double A[6][5] = {
        {0, 0, 0, 0, 0},
        {0.161, 0, 0, 0, 0},
        {-0.008480655492356989, 0.335480655492357, 0, 0, 0},
        {2.8971530571054935, -6.359448489975075, 4.3622954328695815, 0, 0},
        {5.325864828439257, -11.748883564062828, 7.4955393428898365, -0.09249506636175525, 0},
        {5.86145544294642, -12.92096931784711, 8.159367898576159, -0.071584973281401, -0.028269050394068383}};
    const double B[6] = {0.09646076681806523, 0.01, 0.4798896504144996,
                         1.379008574103742, -3.290069515436081, 2.324710524099774};
    double e[6][6];
    for (int i = 0; i < 6; ++i)
        for (int d = 0; d < 6; ++d) e[i][d] = 0.0;
    for (int i = 0; i < 6; ++i) {
        e[i][0] = 1.0;
        for (int j = 0; j < i; ++j)
            for (int d = 0; d < 5; ++d)
                e[i][d + 1] += A[i][j] * e[j][d];
    }
    g[0] = 1.0;
    for (int m = 1; m <= 6; ++m) {
        double s = 0.0;
        for (int i = 0; i < 6; ++i) s += B[i] * e[i][m - 1];
        g[m] = s;
    }
}

extern "C" void kernel_launch(void* const* d_in, const int* in_sizes, int n_in,
                              void* d_out, int out_size, void* d_ws, size_t ws_size,
                              hipStream_t stream)
{
    const float* xs  = (const float*)d_in[0];
    const float* ts  = (const float*)d_in[1];
    const float* es  = (const float*)d_in[2];
    const float* mu0 = (const float*)d_in[3];
    const float* P0  = (const float*)d_in[4];
    const float* A_s = (const float*)d_in[5];
    const float* b_s = (const float*)d_in[6];
    const float* Qch = (const float*)d_in[7];
    const float* Cm  = (const float*)d_in[8];
    const float* Rm  = (const float*)d_in[9];
    const int T = in_sizes[1];

    float* mu_out = (float*)d_out;
    float* P_out  = mu_out + (size_t)T * DZ;

    float* ws = (float*)d_ws;
    float* Ct    = ws;                        // 8192
    float* Rj    = ws + 8192;                 // 4096
    float* Rji   = ws + 12288;                // 4096
    float* mu0u  = ws + 16384;                // 128
    float* p0u   = ws + 16512;                // 16384
    float* wn    = ws + 32896;                // T*16
    float* hbuf  = wn + (size_t)T*16;         // T
    ushortT* Xb  = (ushortT*)(hbuf + T);      // T*MS bf16
    float* elemsA = (float*)(Xb + (size_t)T*MS);
    float* elemsB = elemsA + (size_t)NCH * ESZ;
    float* scr    = elemsB + (size_t)NCH * ESZ;

    const int LCH = (T + NCH - 1) / NCH;

    double g[7];
    compute_gamma(g);
    const float g1 = (float)g[1], g2 = (float)g[2], g3 = (float)g[3], g4 = (float)g[4];

    hipLaunchKernelGGL(kf_wprep, dim3((T + 255)/256), dim3(256), 0, stream,
                       es, ts, wn, hbuf, T);
    hipLaunchKernelGGL(kf_xprep, dim3(256), dim3(NT), 0, stream,
                       A_s, wn, hbuf, Xb, T);
    hipLaunchKernelGGL(kf_prep, dim3(1), dim3(NT), 0, stream,
                       Cm, Rm, mu0, P0, xs, Ct, Rj, Rji, mu0u, p0u, scr);
    hipLaunchKernelGGL(kf_passA, dim3(NCH), dim3(NT), 0, stream,
                       xs, Ct, Rj, Rji, mu0u, p0u, b_s, Qch, wn, hbuf, Xb,
                       elemsA, scr, T, LCH, g1, g2, g3, g4);
    float* bufs[2] = {elemsA, elemsB};
    int cur = 0;
    for (int r = 1; r < NCH; r <<= 1) {
        const int lastj = ((r << 1) >= NCH) ? 1 : 0;
        hipLaunchKernelGGL(kf_scan, dim3(NCH), dim3(NT), 0, stream,
                           bufs[cur], bufs[cur ^ 1], scr, r, lastj);
        cur ^= 1;
    }
    // after log2(NCH)=8 rounds, cur == 0 -> prefix in elemsA, elemsB free for scratch
    hipLaunchKernelGGL(kf_passC, dim3(NCH), dim3(NT), 0, stream,
                       xs, Ct, Rj, mu0u, p0u, b_s, Qch, wn, hbuf, Xb,
                       bufs[cur], mu_out, P_out, bufs[cur ^ 1], T, LCH, g1, g2, g3, g4);
}

// Round 12
// 11278.911 us; speedup vs baseline: 1.0616x; 1.0616x over previous
//
#include <hip/hip_runtime.h>
#include <math.h>

#define DZ 128
#define DX 64
#define KMIX 16
#define JITTER_C 1e-4f
#define MS (DZ*DZ)            // 16384
#define ESZ (4*MS + 2*DZ)     // element: A, At, C, J, b, eta (fp32)
#define NCH 256               // chunks
#define NT 1024               // threads per block (16 waves, 4/SIMD)
#define SCNF (3*MS + 256)     // per-chunk fp32 scratch floats
#define SCNB (3*MS)           // per-chunk bf16 scratch (ushort count)

typedef unsigned short ushortT;
typedef unsigned int uintT;
#define NULF ((float*)nullptr)

// ---------------- bf16 helpers ----------------
__device__ __forceinline__ float b2f(ushortT u){ return __uint_as_float(((uintT)u)<<16); }
__device__ __forceinline__ ushortT f2b(float f){ uintT u=__float_as_uint(f); u += 0x7FFFu + ((u>>16)&1u); return (ushortT)(u>>16); }
__device__ __forceinline__ void ld4(const float* p, float* v){ float4 t=*reinterpret_cast<const float4*>(p); v[0]=t.x;v[1]=t.y;v[2]=t.z;v[3]=t.w; }
__device__ __forceinline__ void ld4(const ushortT* p, float* v){ ushort4 t=*reinterpret_cast<const ushort4*>(p); v[0]=b2f(t.x);v[1]=b2f(t.y);v[2]=b2f(t.z);v[3]=b2f(t.w); }
__device__ __forceinline__ void ld2(const float* p, float* v){ float2 t=*reinterpret_cast<const float2*>(p); v[0]=t.x;v[1]=t.y; }
__device__ __forceinline__ void ld2(const ushortT* p, float* v){ ushort2 t=*reinterpret_cast<const ushort2*>(p); v[0]=b2f(t.x);v[1]=b2f(t.y); }
__device__ __forceinline__ float ld1(const float* p){ return *p; }
__device__ __forceinline__ float ld1(const ushortT* p){ return b2f(*p); }
__device__ __forceinline__ void st1(float* p, float v){ *p = v; }
__device__ __forceinline__ void st1(ushortT* p, float v){ *p = f2b(v); }
__device__ __forceinline__ void st4(float* p, const float* v){ *reinterpret_cast<float4*>(p) = make_float4(v[0],v[1],v[2],v[3]); }
__device__ __forceinline__ void st4(ushortT* p, const float* v){ ushort4 t; t.x=f2b(v[0]);t.y=f2b(v[1]);t.z=f2b(v[2]);t.w=f2b(v[3]); *reinterpret_cast<ushort4*>(p)=t; }
__device__ __forceinline__ void st2(float* p, const float* v){ *reinterpret_cast<float2*>(p) = make_float2(v[0],v[1]); }
__device__ __forceinline__ void st2(ushortT* p, const float* v){ ushort2 t; t.x=f2b(v[0]);t.y=f2b(v[1]); *reinterpret_cast<ushort2*>(p)=t; }

// =====================================================================
// mm_: out[MxN] = op( (At)^T * B ), fp32 accumulate, mixed fp32/bf16 IO.
// MODE 0 store; 1 out+=; 2 aux-; 3 aux+; 4 acc+e1*aux+I (aux may alias out).
// DUAL: also store transpose to outT. Wave-skewed K loop.
// =====================================================================
template<int M,int N,int K,int MODE,bool DUAL,
         typename TA,typename TB,typename TO,typename TX,typename TT>
__device__ void mm_(const TA* __restrict__ At, const TB* __restrict__ B,
                    TO* __restrict__ out, const TX* __restrict__ aux,
                    TT* __restrict__ outT, float e1 = 0.f)
{
    __syncthreads();
    const int tid = threadIdx.x;
    constexpr int TM = M/32, TN = N/32;
    const int tx = tid & 31, ty = tid >> 5;
    const int i0 = ty*TM, j0 = tx*TN;
    float acc[TM*TN];
#pragma unroll
    for (int e = 0; e < TM*TN; ++e) acc[e] = 0.f;
    auto body = [&](int k) {
        const TA* ar = At + k*M + i0;
        const TB* br = B + k*N + j0;
        float av[TM], bv[TN];
        if constexpr (TM == 2) ld2(ar, av);
        else {
#pragma unroll
            for (int a = 0; a < TM; a += 4) ld4(ar + a, av + a);
        }
        if constexpr (TN == 2) ld2(br, bv);
        else {
#pragma unroll
            for (int b = 0; b < TN; b += 4) ld4(br + b, bv + b);
        }
#pragma unroll
        for (int a = 0; a < TM; ++a)
#pragma unroll
            for (int b = 0; b < TN; ++b)
                acc[a*TN+b] = fmaf(av[a], bv[b], acc[a*TN+b]);
    };
    const int off = (tid >> 6) * (K >> 4);
#pragma unroll 8
    for (int k = off; k < K; ++k) body(k);
#pragma unroll 8
    for (int k = 0; k < off; ++k) body(k);
#pragma unroll
    for (int a = 0; a < TM; ++a) {
        if constexpr (TN == 2) {
            const int idx = (i0+a)*N + j0;
            float v[2] = {acc[a*TN], acc[a*TN+1]};
            if constexpr (MODE==1){ float o[2]; ld2(out+idx,o); v[0]+=o[0]; v[1]+=o[1]; }
            else if constexpr (MODE==2){ float o[2]; ld2(aux+idx,o); v[0]=o[0]-v[0]; v[1]=o[1]-v[1]; }
            else if constexpr (MODE==3){ float o[2]; ld2(aux+idx,o); v[0]+=o[0]; v[1]+=o[1]; }
            else if constexpr (MODE==4){ float o[2]; ld2(aux+idx,o);
                const int row=i0+a; v[0]+=e1*o[0]; v[1]+=e1*o[1];
                if(row==j0) v[0]+=1.f; if(row==j0+1) v[1]+=1.f; }
            st2(out+idx, v);
            acc[a*TN]=v[0]; acc[a*TN+1]=v[1];
        } else {
#pragma unroll
            for (int b = 0; b < TN; b += 4) {
                const int idx = (i0+a)*N + j0 + b;
                float v[4] = {acc[a*TN+b],acc[a*TN+b+1],acc[a*TN+b+2],acc[a*TN+b+3]};
                if constexpr (MODE==1){ float o[4]; ld4(out+idx,o);
#pragma unroll
                    for (int q=0;q<4;++q) v[q]+=o[q]; }
                else if constexpr (MODE==2){ float o[4]; ld4(aux+idx,o);
#pragma unroll
                    for (int q=0;q<4;++q) v[q]=o[q]-v[q]; }
                else if constexpr (MODE==3){ float o[4]; ld4(aux+idx,o);
#pragma unroll
                    for (int q=0;q<4;++q) v[q]+=o[q]; }
                else if constexpr (MODE==4){ float o[4]; ld4(aux+idx,o);
                    const int row=i0+a;
#pragma unroll
                    for (int q=0;q<4;++q){ v[q]+=e1*o[q]; if(row==j0+b+q) v[q]+=1.f; } }
                st4(out+idx, v);
#pragma unroll
                for (int q=0;q<4;++q) acc[a*TN+b+q]=v[q];
            }
        }
    }
    if constexpr (DUAL) {
#pragma unroll
        for (int b = 0; b < TN; ++b) {
#pragma unroll
            for (int a = 0; a < TM; a += 4) {
                float v[4] = {acc[(a)*TN+b], acc[(a+1)*TN+b], acc[(a+2)*TN+b], acc[(a+3)*TN+b]};
                st4(outT + (j0+b)*M + i0 + a, v);
            }
        }
    }
    __syncthreads();
}

// =====================================================================
// mv_: out[i] = op(aux[i], sum_k At[k*M+i]*v[k]) — NT/M threads per row.
// =====================================================================
template<int M,int K,int MODE,typename TAt>
__device__ void mv_(const TAt* __restrict__ At, const float* __restrict__ v,
                    float* __restrict__ out, const float* __restrict__ aux)
{
    __syncthreads();
    const int tid = threadIdx.x;
    constexpr int TPR = NT / M;
    constexpr int CH  = K / TPR;
    const int r  = tid / TPR;
    const int sg = tid % TPR;
    const int k0 = sg * CH;
    float s = 0.f;
#pragma unroll
    for (int k = 0; k < CH; ++k)
        s = fmaf(ld1(At + (k0 + k)*M + r), v[k0 + k], s);
#pragma unroll
    for (int o = 1; o < TPR; o <<= 1) s += __shfl_xor(s, o);
    if (sg == 0) {
        float rr;
        if constexpr (MODE == 0) rr = s;
        else if constexpr (MODE == 1) rr = aux[r] + s;
        else rr = aux[r] - s;
        out[r] = rr;
    }
    __syncthreads();
}

// dst[NxM] = src[MxN]^T via XOR-swizzled LDS bounce (128x128 only).
__device__ void trans_g(const float* __restrict__ src, float* __restrict__ dst,
                        float* __restrict__ Lb)
{
    __syncthreads();
    for (int e = threadIdx.x; e < MS; e += NT) {
        int i = e >> 7, j = e & 127;
        Lb[(i << 7) + (j ^ (i & 31))] = src[e];
    }
    __syncthreads();
    for (int e = threadIdx.x; e < MS; e += NT) {
        int a = e >> 7, b = e & 127;
        dst[e] = Lb[(b << 7) + (a ^ (b & 31))];
    }
    __syncthreads();
}

// =====================================================================
// gj64_spd: rank-4 block Gauss-Jordan inverse of SPD 64x64 in LDS.
// =====================================================================
__device__ void gj64_spd(float* __restrict__ A, float* __restrict__ st)
{
    const int tid = threadIdx.x;
    for (int p = 0; p < DX; p += 4) {
        __syncthreads();
        if (tid < 64) {
#pragma unroll
            for (int b = 0; b < 4; ++b) st[tid*4+b] = A[tid*DX + p + b];
        } else if (tid < 128) {
            int j = tid - 64;
#pragma unroll
            for (int b = 0; b < 4; ++b) st[256 + b*64 + j] = A[(p+b)*DX + j];
        }
        __syncthreads();
        float Dm[16], Di[16];
#pragma unroll
        for (int a = 0; a < 4; ++a)
#pragma unroll
            for (int b = 0; b < 4; ++b) {
                Dm[a*4+b] = st[(p+a)*4 + b];
                Di[a*4+b] = (a==b) ? 1.f : 0.f;
            }
#pragma unroll
        for (int q = 0; q < 4; ++q) {
            float rp = 1.f / Dm[q*4+q];
#pragma unroll
            for (int j = 0; j < 4; ++j) { Dm[q*4+j] *= rp; Di[q*4+j] *= rp; }
#pragma unroll
            for (int i = 0; i < 4; ++i) {
                if (i == q) continue;
                float f = Dm[i*4+q];
#pragma unroll
                for (int j = 0; j < 4; ++j) { Dm[i*4+j] = fmaf(-f, Dm[q*4+j], Dm[i*4+j]); Di[i*4+j] = fmaf(-f, Di[q*4+j], Di[i*4+j]); }
            }
        }
        for (int e = tid; e < DX*DX; e += NT) {
            const int i = e >> 6, j = e & 63;
            const bool iP = (i >= p) && (i < p+4);
            const bool jP = (j >= p) && (j < p+4);
            float o;
            if (iP && jP) {
                o = Di[(i-p)*4 + (j-p)];
            } else if (iP) {
                const int a = i - p;
                o = Di[a*4+0]*st[256+0*64+j] + Di[a*4+1]*st[256+1*64+j]
                  + Di[a*4+2]*st[256+2*64+j] + Di[a*4+3]*st[256+3*64+j];
            } else {
                float Ei[4];
#pragma unroll
                for (int b = 0; b < 4; ++b)
                    Ei[b] = st[i*4+0]*Di[0*4+b] + st[i*4+1]*Di[1*4+b]
                          + st[i*4+2]*Di[2*4+b] + st[i*4+3]*Di[3*4+b];
                if (jP) o = -Ei[j-p];
                else    o = A[e] - (Ei[0]*st[256+0*64+j] + Ei[1]*st[256+1*64+j]
                                  + Ei[2]*st[256+2*64+j] + Ei[3]*st[256+3*64+j]);
            }
            A[e] = o;
        }
    }
    __syncthreads();
}

// =====================================================================
// gj128_piv: partial-pivoted GJ of 128x128 in LDS; wave-0 shfl argmax.
// =====================================================================
__device__ void gj128_piv(float* __restrict__ A, float* __restrict__ pc, float* __restrict__ pr,
                          int* __restrict__ rec, int* __restrict__ ipv1)
{
    __syncthreads();
    const int tid = threadIdx.x;
    for (int p = 0; p < DZ; ++p) {
        if (tid < 64) {
            float best = -1.f; int bi = p;
            for (int i = tid; i < DZ; i += 64) {
                float v = (i >= p) ? fabsf(A[i*DZ + p]) : -2.f;
                if (v > best) { best = v; bi = i; }
            }
            for (int off = 32; off > 0; off >>= 1) {
                float ob = __shfl_xor(best, off);
                int obi = __shfl_xor(bi, off);
                if (ob > best) { best = ob; bi = obi; }
            }
            if (tid == 0) { rec[p] = bi; ipv1[0] = bi; }
        }
        __syncthreads();
        const int r = ipv1[0];
        if (r != p) {
            for (int j = tid; j < DZ; j += NT) { float t = A[p*DZ+j]; A[p*DZ+j] = A[r*DZ+j]; A[r*DZ+j] = t; }
            __syncthreads();
        }
        if (tid < DZ) { pc[tid] = A[tid*DZ + p]; pr[tid] = A[p*DZ + tid]; }
        __syncthreads();
        const float rp = 1.f / pr[p];
        for (int e = tid; e < MS; e += NT) {
            const int i = e >> 7, j = e & 127;
            const float pv = pr[j] * rp;
            float o;
            if (i == p) o = (j == p) ? rp : pv;
            else { const float fc = pc[i]; o = (j == p) ? (-fc*rp) : (A[e] - fc*pv); }
            A[e] = o;
        }
        __syncthreads();
    }
    for (int p = DZ - 1; p >= 0; --p) {
        const int r = rec[p];
        if (r != p) {
            for (int i = tid; i < DZ; i += NT) { float t = A[i*DZ+p]; A[i*DZ+p] = A[i*DZ+r]; A[i*DZ+r] = t; }
            __syncthreads();
        }
    }
    __syncthreads();
}

// =====================================================================
// phase1_dev: slim step map (||X|| ~ 1e-2), X from A_s directly:
//   F = I + g1 X + (g2 I + g3 X) X^2      -> Ft in L0 (LDS)
//   Q = h (g1 D + W1 D + D W1^T)          -> b3 (bf16)
//   c = h (g1 + g2 X + g3 X^2 + g4 X^3) eb -> cvec
// X2/X2t -> b1/b2 (bf16); X kept in f1 (fp32, reused by callers).
// =====================================================================
__device__ void phase1_dev(int k,
    const float* __restrict__ A_s, const float* __restrict__ b_s,
    const float* __restrict__ Qch, const float* __restrict__ es, const float* __restrict__ ts,
    float* f1, ushortT* b1, ushortT* b2, ushortT* b3,
    float* L0, float* L1,
    float* W16, float* ebv, float* eqv, float* vvv, float* cvec,
    float g1, float g2, float g3, float g4)
{
    const int tid = threadIdx.x;
    const float h = ts[k] - ts[k-1];
    if (h <= 0.f) {
        __syncthreads();
        for (int e = tid; e < MS; e += NT) {
            int i = e >> 7, j = e & 127;
            L0[e] = (i==j) ? 1.f : 0.f;
            st1(b3 + e, 0.f);
        }
        if (tid < DZ) cvec[tid] = 0.f;
        __syncthreads();
        return;
    }
    __syncthreads();
    if (tid < KMIX) W16[tid] = es[(size_t)k*KMIX + tid];
    __syncthreads();
    if (tid == 0) {
        float s = 0.f;
        for (int m = 0; m < KMIX; ++m) s += W16[m];
        float inv = 1.f/s;
        for (int m = 0; m < KMIX; ++m) W16[m] *= inv;
    }
    __syncthreads();
    if (tid < DZ) {
        float eb = 0.f, eq = 0.f;
        for (int m = 0; m < KMIX; ++m) {
            float wm = W16[m];
            eb = fmaf(wm, b_s[m*DZ+tid], eb);
            float qc = Qch[m*DZ+tid];
            eq = fmaf(wm, qc*qc, eq);
        }
        ebv[tid] = eb; eqv[tid] = eq;
    }
    // X = h * sum_m w_m A_s[m] -> L1 (X), f1 (X), L0 (Xt); wave-skewed m-loop
    const int tx = tid & 31, ty = tid >> 5;
    const int i0 = ty*4, j0 = tx*4;
    float t16[16];
#pragma unroll
    for (int e = 0; e < 16; ++e) t16[e] = 0.f;
    {
        const int mq = (tid >> 6) & (KMIX - 1);
        for (int mi = 0; mi < KMIX; ++mi) {
            int m = mi + mq; if (m >= KMIX) m -= KMIX;
            float wm = W16[m];
            const float* Am = A_s + (size_t)m * MS;
#pragma unroll
            for (int a = 0; a < 4; ++a) {
                float4 p0 = *reinterpret_cast<const float4*>(&Am[(i0+a)*DZ + j0]);
                t16[a*4+0]=fmaf(wm,p0.x,t16[a*4+0]); t16[a*4+1]=fmaf(wm,p0.y,t16[a*4+1]);
                t16[a*4+2]=fmaf(wm,p0.z,t16[a*4+2]); t16[a*4+3]=fmaf(wm,p0.w,t16[a*4+3]);
            }
        }
    }
#pragma unroll
    for (int a = 0; a < 4; ++a)
#pragma unroll
        for (int b = 0; b < 4; ++b) {
            float v = h * t16[a*4+b];
            L1[(i0+a)*DZ + (j0+b)] = v;
            f1[(i0+a)*DZ + (j0+b)] = v;
            L0[(j0+b)*DZ + (i0+a)] = v;
        }
    __syncthreads();
    // cvec: 3 power iterations (terms through g4 X^3)
    {
        float gg[5]; gg[1]=g1; gg[2]=g2; gg[3]=g3; gg[4]=g4;
        if (tid < DZ) vvv[tid] = ebv[tid];
        float creg = (tid < DZ) ? g1 * ebv[tid] : 0.f;
        __syncthreads();
        for (int m = 1; m <= 3; ++m) {
            float vn = 0.f;
            if (tid < DZ)
                for (int kk = 0; kk < DZ; ++kk)
                    vn = fmaf(L0[kk*DZ + tid], vvv[kk], vn);
            __syncthreads();
            if (tid < DZ) vvv[tid] = vn;
            creg = fmaf(gg[m+1], vn, creg);
            __syncthreads();
        }
        if (tid < DZ) cvec[tid] = h * creg;
    }
    // X2 (dual, bf16)
    mm_<128,128,128,0,true>(L0, L1, b1, NULF, b2);
    // Q -> b3 (bf16) ; Mt = g2 I + g3 Xt -> L1
    for (int e = tid; e < MS; e += NT) {
        int j = e >> 7, i = e & 127;   // j=row, i=col
        float xt = L0[e];
        float w1  = g2*f1[e] + g3*ld1(b1+e);
        float w1t = g2*xt    + g3*ld1(b2+e);
        float vq = w1*eqv[i] + eqv[j]*w1t;
        if (i == j) vq += g1*eqv[j];
        st1(b3 + e, h * vq);
        L1[e] = g3*xt + ((i==j) ? g2 : 0.f);
    }
    __syncthreads();
    // Ft = X2^T Mt + g1 Xt + I  -> L0 (MODE 4, aux aliases out, per-tile safe)
    mm_<128,128,128,4,false>(b1, L1, L0, (const float*)L0, NULF, g1);
}

#define SHARED_DECLS \
    __shared__ __align__(16) float L0[MS]; \
    __shared__ __align__(16) float L1[MS]; \
    __shared__ __align__(16) float SL[DX*DX]; \
    __shared__ __align__(16) float GJB[520]; \
    __shared__ float V0[DZ],V1[DZ],V2[DZ],V3[DZ],V4[DZ],V5[DZ]; \
    __shared__ float r64s[DX], u64s[DX]; \
    __shared__ float W16[KMIX], ebv[DZ], eqv[DZ], vvv[DZ], cvec[DZ]; \
    __shared__ float GJc[DZ], GJr[DZ]; \
    __shared__ int REC[DZ]; __shared__ int IPV1[1];

// =====================================================================
// prep: Ct, Rj, Rji, initial updated state (mu0u, p0u)
// =====================================================================
__global__ __launch_bounds__(NT) void kf_prep(
    const float* __restrict__ Cm, const float* __restrict__ Rm,
    const float* __restrict__ mu0, const float* __restrict__ P0,
    const float* __restrict__ xs,
    float* Ct, float* Rj, float* Rji, float* mu0u, float* p0u, float* scr)
{
    SHARED_DECLS
    const int tid = threadIdx.x;
    for (int i = tid; i < DZ*DX; i += NT) { int z = i>>6, m = i&63; Ct[i] = Cm[m*DZ + z]; }
    for (int i = tid; i < DX*DX; i += NT) {
        int a = i>>6, b = i&63;
        float v = Rm[i] + ((a==b) ? JITTER_C : 0.f);
        Rj[i] = v; SL[i] = v;
    }
    gj64_spd(SL, GJB);
    for (int i = tid; i < DX*DX; i += NT) Rji[i] = SL[i];
    float* z  = scr;
    float* cp = scr + DZ*DX;
    float* kt = scr + MS;
    mm_<128,64,128,0,true>(P0, Ct, z, NULF, cp);
    mm_<64,64,128,3,false>(Ct, z, SL, Rj, NULF);
    gj64_spd(SL, GJB);
    mm_<64,128,64,0,false>(SL, cp, kt, NULF, NULF);
    mv_<64,128,2>(Ct, mu0, r64s, xs);
    mv_<128,64,1>(kt, r64s, mu0u, mu0);
    mm_<128,128,64,2,false>(kt, cp, p0u, P0, NULF);
    __syncthreads();
    for (int e = tid; e < MS; e += NT) L0[e] = p0u[e];
    __syncthreads();
    for (int e = tid; e < MS; e += NT) {
        int i = e>>7, j = e&127;
        p0u[e] = 0.5f * (L0[e] + L0[j*DZ + i]);
    }
}

// =====================================================================
// pass A: per chunk, element recursion (predict + Woodbury update)
// fp32 scratch f1..f3; bf16 scratch b1..b3 (X2/X2t/Q only)
// =====================================================================
__global__ __launch_bounds__(NT) void kf_passA(
    const float* __restrict__ A_s, const float* __restrict__ b_s,
    const float* __restrict__ Qch, const float* __restrict__ es,
    const float* __restrict__ ts, const float* __restrict__ xs,
    const float* __restrict__ Ct, const float* __restrict__ Rj,
    const float* __restrict__ Rji,
    const float* __restrict__ mu0u, const float* __restrict__ p0u,
    float* elems, float* scrF, ushortT* scrB, int T, int LCH,
    float g1, float g2, float g3, float g4)
{
    SHARED_DECLS
    const int c = blockIdx.x, tid = threadIdx.x;
    float* f1 = scrF + (size_t)c * SCNF;
    float* f2 = f1 + MS;
    float* f3 = f1 + 2*MS;
    ushortT* b1 = scrB + (size_t)c * SCNB;
    ushortT* b2 = b1 + MS;
    ushortT* b3 = b1 + 2*MS;
    float* R = elems + (size_t)c * ESZ;
    float* RAs = R; float* RAts = R+MS; float* RCs = R+2*MS; float* RJs = R+3*MS;
    float* Rbs = R+4*MS; float* Rhs = R+4*MS+DZ;
    int eBeg = c*LCH, eEnd = (c*LCH + LCH < T) ? (c*LCH + LCH) : T;
    if (eBeg >= eEnd && c != 0) {
        for (int e = tid; e < MS; e += NT) {
            int i = e>>7, j = e&127; float id = (i==j)?1.f:0.f;
            RAs[e]=id; RAts[e]=id; RCs[e]=0.f; RJs[e]=0.f;
        }
        if (tid < DZ) { Rbs[tid]=0.f; Rhs[tid]=0.f; }
        return;
    }
    if (c == 0) {
        for (int e = tid; e < MS; e += NT) { RAs[e]=0.f; RCs[e]=p0u[e]; RJs[e]=0.f; }
        if (tid < DZ) { V0[tid]=mu0u[tid]; V5[tid]=0.f; }
        eBeg = 1;
    } else {
        for (int e = tid; e < MS; e += NT) {
            int i = e>>7, j = e&127;
            RAs[e] = (i==j)?1.f:0.f; RCs[e]=0.f; RJs[e]=0.f;
        }
        if (tid < DZ) { V0[tid]=0.f; V5[tid]=0.f; }
    }
    __syncthreads();
    float* z  = L0;    float* zt = L0 + 8192;
    for (int e = eBeg; e < eEnd; ++e) {
        phase1_dev(e, A_s,b_s,Qch,es,ts, f1,b1,b2,b3, L0,L1,
                   W16,ebv,eqv,vvv,cvec, g1,g2,g3,g4);
        // ---- predict-compose (EJ=0); Ft in L0, Q in b3 ----
        mm_<128,128,128,0,false>(L0, RAs, f2, NULF, NULF);         // tA -> f2 (X dead soon)
        mv_<128,128,1>(L0, V0, V1, cvec);                          // Rb' = F Rb + c
        mm_<128,128,128,0,false>(RCs, L0, f1, NULF, NULF);         // tU -> f1 (X dead)
        mm_<128,128,128,3,false>(L0, f1, L1, b3, NULF);            // RC' = F tU + Q -> L1
        // ---- update-compose (Woodbury); Z/Zt in LDS ----
        mm_<128,64,128,0,true>(L1, Ct, z, NULF, zt);               // Z dual (LDS)
        mm_<64,64,128,3,false>(Ct, z, SL, Rj, NULF);               // S~ = R~ + C Z
        gj64_spd(SL, GJB);                                         // SL = S~^-1
        mm_<64,128,128,0,false>(Ct, f2, f3, NULF, NULF);           // y = C tA -> f3
        mm_<64,128,64,0,false>(SL, f3, f3 + 8192, NULF, NULF);     // hh = Si y
        mm_<128,128,64,2,false>(zt, f3 + 8192, RAs, f2, NULF);     // RA'' = tA - Z hh
        mm_<128,128,64,1,false>(f3, f3 + 8192, RJs, NULF, NULF);   // RJ += y^T hh
        mm_<64,128,64,0,false>(SL, zt, f1, NULF, NULF);            // h2 = Si Z^T (tU dead)
        mm_<128,128,64,2,false>(zt, f1, RCs, (const float*)L1, NULF); // RC'' = RC' - Z h2
        // vectors
        mv_<64,128,2>(Ct, V1, r64s, xs + (size_t)e*DX);            // r = x - C Rb'
        mv_<64,64,0>(Rji, xs + (size_t)e*DX, u64s, NULF);          // u = R~i x
        mv_<128,64,1>(zt, u64s, V2, V1);                           // v1 = Rb' + Z u
        mv_<64,128,0>(Ct, V2, GJc, NULF);                          // w = C v1
        mv_<64,64,0>(SL, GJc, GJr, NULF);                          // w2 = Si w
        mv_<128,64,2>(zt, GJr, V0, V2);                            // Rb'' = v1 - Z w2
        mv_<64,64,0>(SL, r64s, u64s, NULF);                        // s = Si r
        mv_<128,64,1>(f3, u64s, V5, V5);                           // Reta += y^T s
    }
    __syncthreads();
    if (tid < DZ) { Rbs[tid] = V0[tid]; Rhs[tid] = V5[tid]; }
    trans_g(RAs, RAts, L0);
}

// =====================================================================
// combine: Rd <- Rd (earlier) (x) E (later).  t1/t3 live in L1 (LDS).
// lastj: only RC/Rb needed.
// =====================================================================
__device__ void combine(float* Rd,
    const float* EA, const float* EAt, const float* EC, const float* EJ,
    const float* Ebg, const float* Ehg,
    float* t2, float* t3,
    float* L0, float* L1,
    float* V0, float* V1, float* V2, float* V3, float* V4, float* V5,
    float* GJc, float* GJr, int* REC, int* IPV1, int lastj)
{
    float* RA = Rd; float* RAt = Rd+MS; float* RC = Rd+2*MS; float* RJ = Rd+3*MS;
    float* Rb = Rd+4*MS; float* Rh = Rd+4*MS+DZ;
    const int tid = threadIdx.x;
    __syncthreads();
    if (tid < DZ) { V0[tid]=Ebg[tid]; V1[tid]=Ehg[tid]; V2[tid]=Rb[tid]; }
    mm_<128,128,128,0,false>(EJ, RC, L0, NULF, NULF);          // L0 = EJ RC
    if (tid < DZ) L0[tid*DZ + tid] += 1.f;                     // M^T
    gj128_piv(L0, GJc, GJr, REC, IPV1);                        // L0 = M^-T
    if (!lastj) {
        mm_<128,128,128,0,false>(L0, RA, L1, NULF, NULF);          // t1 = Minv RA (LDS)
        mm_<128,128,128,0,false>(EJ, RA, t2, NULF, NULF);          // t2 = EJ RA
        mm_<128,128,128,1,false>(L1, t2, RJ, NULF, NULF);          // RJ += t1^T t2
        mv_<128,128,2>(EJ, V2, V4, V1);                            // w1 = Eh - EJ Rb
        mv_<128,128,1>(L1, V4, Rh, Rh);                            // Rh += t1^T w1
    }
    mv_<128,128,1>(RC, V1, V3, V2);                            // v1 = Rb + RC Eh
    mv_<128,128,0>(L0, V3, V5, NULF);                          // z1 = Minv v1
    mv_<128,128,1>(EAt, V5, Rb, V0);                           // Rb = Eb + EA z1
    mm_<128,128,128,0,false>(L0, RC, t3, NULF, NULF);          // t3 = Minv RC
    mm_<128,128,128,0,false>(t3, EAt, t2, NULF, NULF);         // t2 = (Minv RC)^T EA^T
    mm_<128,128,128,3,false>(EAt, t2, RC, EC, NULF);           // RC = EA t2 + EC
    if (!lastj) {
        mm_<128,128,128,0,false>(EAt, L1, RA, NULF, NULF);         // RA = EA t1
        trans_g(RA, RAt, L1);
    }
}

// =====================================================================
// Kogge-Stone scan round
// =====================================================================
__global__ __launch_bounds__(NT) void kf_scan(
    const float* __restrict__ in, float* __restrict__ out, float* scrF, int r, int lastj)
{
    SHARED_DECLS
    const int c = blockIdx.x;
    float* sc = scrF + (size_t)c * SCNF;
    float* dst = out + (size_t)c * ESZ;
    const float* src = in + (size_t)((c >= r) ? (c - r) : c) * ESZ;
    if (lastj) {
        for (int e = threadIdx.x; e < MS; e += NT) dst[2*MS + e] = src[2*MS + e];
        for (int e = threadIdx.x; e < DZ; e += NT) dst[4*MS + e] = src[4*MS + e];
    } else {
        for (int e = threadIdx.x; e < ESZ; e += NT) dst[e] = src[e];
    }
    if (c >= r) {
        const float* E = in + (size_t)c * ESZ;
        combine(dst, E, E+MS, E+2*MS, E+3*MS, E+4*MS, E+4*MS+DZ,
                sc, sc + MS, L0, L1,
                V0,V1,V2,V3,V4,V5, GJc, GJr, REC, IPV1, lastj);
    }
}

// =====================================================================
// pass C: plain filter from exact boundary state; writes outputs.
// =====================================================================
__global__ __launch_bounds__(NT) void kf_passC(
    const float* __restrict__ A_s, const float* __restrict__ b_s,
    const float* __restrict__ Qch, const float* __restrict__ es,
    const float* __restrict__ ts, const float* __restrict__ xs,
    const float* __restrict__ Ct, const float* __restrict__ Rj,
    const float* __restrict__ mu0u, const float* __restrict__ p0u,
    const float* __restrict__ pfx,
    float* mu_out, float* P_out, float* scrF, ushortT* scrB, int T, int LCH,
    float g1, float g2, float g3, float g4)
{
    SHARED_DECLS
    const int c = blockIdx.x, tid = threadIdx.x;
    float* f1 = scrF + (size_t)c * SCNF;
    float* f2 = f1 + MS;
    float* P  = f1 + 2*MS;
    ushortT* b1 = scrB + (size_t)c * SCNB;
    ushortT* b2 = b1 + MS;
    ushortT* b3 = b1 + 2*MS;
    int eBeg = c*LCH, eEnd = (c*LCH + LCH < T) ? (c*LCH + LCH) : T;
    if (eBeg >= eEnd && c != 0) return;
    if (c == 0) {
        for (int e = tid; e < MS; e += NT) { float v = p0u[e]; P[e] = v; P_out[e] = v; }
        if (tid < DZ) { V0[tid] = mu0u[tid]; mu_out[tid] = mu0u[tid]; }
        eBeg = 1;
    } else {
        const float* X = pfx + (size_t)(c-1) * ESZ;
        for (int e = tid; e < MS; e += NT) P[e] = X[2*MS + e];
        if (tid < DZ) V0[tid] = X[4*MS + tid];
    }
    __syncthreads();
    float* z  = L0;    float* zt = L0 + 8192;
    for (int e = eBeg; e < eEnd; ++e) {
        phase1_dev(e, A_s,b_s,Qch,es,ts, f1,b1,b2,b3, L0,L1,
                   W16,ebv,eqv,vvv,cvec, g1,g2,g3,g4);
        mm_<128,128,128,0,false>(P, L0, f2, NULF, NULF);           // U -> f2
        mm_<128,128,128,3,false>(L0, f2, L1, b3, NULF);            // Ppr = F U + Q -> L1
        mv_<128,128,1>(L0, V0, V1, cvec);                          // mupr = F mu + c
        mm_<128,64,128,0,true>(L1, Ct, z, NULF, zt);               // Z dual (LDS)
        mm_<64,64,128,3,false>(Ct, z, SL, Rj, NULF);               // S
        gj64_spd(SL, GJB);
        mm_<64,128,64,0,false>(SL, zt, f1, NULF, NULF);            // kt = Si Z^T (X dead)
        mv_<64,128,2>(Ct, V1, r64s, xs + (size_t)e*DX);            // y = x - C mupr
        mv_<128,64,1>(f1, r64s, V0, V1);                           // mu = mupr + K y
        if (tid < DZ) mu_out[(size_t)e*DZ + tid] = V0[tid];
        mm_<128,128,64,2,false>(zt, f1, L1, (const float*)L1, NULF); // P_u in L1
        for (int ee = tid; ee < MS; ee += NT) {
            int i = ee >> 7, j = ee & 127;
            L0[(i << 7) + (j ^ (i & 31))] = L1[ee];
        }
        __syncthreads();
        float* po = P_out + (size_t)e * MS;
        for (int ee = tid; ee < MS; ee += NT) {
            int i = ee >> 7, j = ee & 127;
            float v = 0.5f * (L1[ee] + L0[(j << 7) + (i ^ (j & 31))]);
            P[ee] = v;
            __builtin_nontemporal_store(v, &po[ee]);
        }
        __syncthreads();
    }
}

// =====================================================================
// host: RK stability polynomial coefficients
// =====================================================================
static void compute_gamma(double g[7])
{
    const double A[6][5] = {
        {0, 0, 0, 0, 0},
        {0.161, 0, 0, 0, 0},
        {-0.008480655492356989, 0.335480655492357, 0, 0, 0},
        {2.8971530571054935, -6.359448489975075, 4.3622954328695815, 0, 0},
        {5.325864828439257, -11.748883564062828, 7.4955393428898365, -0.09249506636175525, 0},
        {5.86145544294642, -12.92096931784711, 8.159367898576159, -0.071584973281401, -0.028269050394068383}};
    const double B[6] = {0.09646076681806523, 0.01, 0.4798896504144996,
                         1.379008574103742, -3.290069515436081, 2.324710524099774};
    double e[6][6];
    for (int i = 0; i < 6; ++i)
        for (int d = 0; d < 6; ++d) e[i][d] = 0.0;
    for (int i = 0; i < 6; ++i) {
        e[i][0] = 1.0;
        for (int j = 0; j < i; ++j)
            for (int d = 0; d < 5; ++d)
                e[i][d + 1] += A[i][j] * e[j][d];
    }
    g[0] = 1.0;
    for (int m = 1; m <= 6; ++m) {
        double s = 0.0;
        for (int i = 0; i < 6; ++i) s += B[i] * e[i][m - 1];
        g[m] = s;
    }
}

extern "C" void kernel_launch(void* const* d_in, const int* in_sizes, int n_in,
                              void* d_out, int out_size, void* d_ws, size_t ws_size,
                              hipStream_t stream)
{
    const float* xs  = (const float*)d_in[0];
    const float* ts  = (const float*)d_in[1];
    const float* es  = (const float*)d_in[2];
    const float* mu0 = (const float*)d_in[3];
    const float* P0  = (const float*)d_in[4];
    const float* A_s = (const float*)d_in[5];
    const float* b_s = (const float*)d_in[6];
    const float* Qch = (const float*)d_in[7];
    const float* Cm  = (const float*)d_in[8];
    const float* Rm  = (const float*)d_in[9];
    const int T = in_sizes[1];

    float* mu_out = (float*)d_out;
    float* P_out  = mu_out + (size_t)T * DZ;

    char* p = (char*)d_ws;
    auto alloc = [&](size_t bytes){ char* r = p; p += (bytes + 255) & ~(size_t)255; return r; };
    float* Ct    = (float*)alloc(8192*4);
    float* Rj    = (float*)alloc(4096*4);
    float* Rji   = (float*)alloc(4096*4);
    float* mu0u  = (float*)alloc(DZ*4);
    float* p0u   = (float*)alloc((size_t)MS*4);
    float* elemsA = (float*)alloc((size_t)NCH*ESZ*4);
    float* elemsB = (float*)alloc((size_t)NCH*ESZ*4);
    float* scrF  = (float*)alloc((size_t)NCH*SCNF*4);
    ushortT* scrB = (ushortT*)alloc((size_t)NCH*SCNB*2);

    const int LCH = (T + NCH - 1) / NCH;

    double g[7];
    compute_gamma(g);
    const float g1 = (float)g[1], g2 = (float)g[2], g3 = (float)g[3], g4 = (float)g[4];

    hipLaunchKernelGGL(kf_prep, dim3(1), dim3(NT), 0, stream,
                       Cm, Rm, mu0, P0, xs, Ct, Rj, Rji, mu0u, p0u, scrF);
    hipLaunchKernelGGL(kf_passA, dim3(NCH), dim3(NT), 0, stream,
                       A_s, b_s, Qch, es, ts, xs, Ct, Rj, Rji, mu0u, p0u,
                       elemsA, scrF, scrB, T, LCH, g1, g2, g3, g4);
    float* bufs[2] = {elemsA, elemsB};
    int cur = 0;
    for (int r = 1; r < NCH; r <<= 1) {
        const int lastj = ((r << 1) >= NCH) ? 1 : 0;
        hipLaunchKernelGGL(kf_scan, dim3(NCH), dim3(NT), 0, stream,
                           bufs[cur], bufs[cur ^ 1], scrF, r, lastj);
        cur ^= 1;
    }
    hipLaunchKernelGGL(kf_passC, dim3(NCH), dim3(NT), 0, stream,
                       A_s, b_s, Qch, es, ts, xs, Ct, Rj, mu0u, p0u,
                       bufs[cur], mu_out, P_out, scrF, scrB, T, LCH, g1, g2, g3, g4);
}